// Round 1
// baseline (369.402 us; speedup 1.0000x reference)
//
#include <hip/hip_runtime.h>
#include <math.h>

#define NOCT 5
#define HH 1024
#define WW 1024
#define NCH 48

// ---- ordered-uint float min/max keys ----
static __device__ __forceinline__ unsigned f2key(float f) {
    unsigned u = __float_as_uint(f);
    return (u & 0x80000000u) ? ~u : (u | 0x80000000u);
}
static __device__ __forceinline__ float key2f(unsigned k) {
    return __uint_as_float((k & 0x80000000u) ? (k ^ 0x80000000u) : ~k);
}

// table offsets per octave: sizes (res+1)^2, res = 4<<o
// 25, 81, 289, 1089, 4225  -> offsets 0,25,106,395,1484 ; total 5709
#define GTAB_TOTAL 5709

// K1: cos/sin tables + init min/max atomics
__global__ void k_tables(const float* __restrict__ a0, const float* __restrict__ a1,
                         const float* __restrict__ a2, const float* __restrict__ a3,
                         const float* __restrict__ a4,
                         float2* __restrict__ gtab, unsigned* __restrict__ mm) {
    int t = blockIdx.x * 256 + threadIdx.x;
    if (t < 2 * NOCT) mm[t] = (t < NOCT) ? 0xFFFFFFFFu : 0u;  // min slots, max slots
    if (t >= GTAB_TOTAL) return;
    const int offs[6] = {0, 25, 106, 395, 1484, 5709};
    int o = 0;
    while (t >= offs[o + 1]) ++o;
    int li = t - offs[o];
    const float* ap = (o == 0) ? a0 : (o == 1) ? a1 : (o == 2) ? a2 : (o == 3) ? a3 : a4;
    float s, c;
    sincosf(ap[li], &s, &c);
    gtab[t] = make_float2(c, s);  // g[0]=cos, g[1]=sin
}

// perlin noise for 4 consecutive pixels (same row, same cell in x since nx>=16)
static __device__ __forceinline__ void perlin4(const float2* __restrict__ gtab, int o,
                                               int i, int j, float sy, const float sx[4],
                                               float n[4]) {
    const int offs[5] = {0, 25, 106, 395, 1484};
    const int res = 4 << o;
    const int sh = 8 - o;          // ny = nx = 2^(8-o)
    float ty = (float)res * sy;    // exact: res is power of two
    float P0 = ty - floorf(ty);
    int cy = i >> sh, cx = j >> sh;
    int stride = res + 1;
    int base = offs[o] + cy * stride + cx;
    float2 g00 = gtab[base],          g01 = gtab[base + 1];
    float2 g10 = gtab[base + stride], g11 = gtab[base + stride + 1];
    float wy  = P0 * P0 * (3.0f - 2.0f * P0);
    float P0m = P0 - 1.0f;
#pragma unroll
    for (int k = 0; k < 4; ++k) {
        float tx  = (float)res * sx[k];
        float P1  = tx - floorf(tx);
        float P1m = P1 - 1.0f;
        float n00 = P0  * g00.x + P1  * g00.y;
        float n10 = P0m * g10.x + P1  * g10.y;
        float n01 = P0  * g01.x + P1m * g01.y;
        float n11 = P0m * g11.x + P1m * g11.y;
        float n0 = n00 + wy * (n10 - n00);
        float n1 = n01 + wy * (n11 - n01);
        float wx = P1 * P1 * (3.0f - 2.0f * P1);
        n[k] = n0 + wx * (n1 - n0);
    }
}

// K2: per-octave global min/max over the 1024x1024 noise field
__global__ __launch_bounds__(256) void k_minmax(const float2* __restrict__ gtab,
                                                unsigned* __restrict__ mm) {
    float mn[NOCT], mx[NOCT];
#pragma unroll
    for (int o = 0; o < NOCT; ++o) { mn[o] = INFINITY; mx[o] = -INFINITY; }

    int tid = blockIdx.x * 256 + threadIdx.x;          // 0..65535 (256 blocks)
    for (int q = tid; q < (HH * WW / 4); q += 256 * 256) {
        int pix = q << 2;
        int i = pix >> 10;
        int j = pix & 1023;
        float sy = (float)i / 1023.0f;                  // true divide: exact 1.0 at 1023
        float sx[4];
#pragma unroll
        for (int k = 0; k < 4; ++k) sx[k] = (float)(j + k) / 1023.0f;
#pragma unroll
        for (int o = 0; o < NOCT; ++o) {
            float n[4];
            perlin4(gtab, o, i, j, sy, sx, n);
#pragma unroll
            for (int k = 0; k < 4; ++k) {
                mn[o] = fminf(mn[o], n[k]);
                mx[o] = fmaxf(mx[o], n[k]);
            }
        }
    }

    __shared__ float smn[NOCT][4], smx[NOCT][4];
    int lane = threadIdx.x & 63, wv = threadIdx.x >> 6;
#pragma unroll
    for (int o = 0; o < NOCT; ++o) {
        float a = mn[o], b = mx[o];
#pragma unroll
        for (int d = 32; d > 0; d >>= 1) {
            a = fminf(a, __shfl_xor(a, d, 64));
            b = fmaxf(b, __shfl_xor(b, d, 64));
        }
        if (lane == 0) { smn[o][wv] = a; smx[o][wv] = b; }
    }
    __syncthreads();
    if (threadIdx.x < NOCT) {
        int o = threadIdx.x;
        float a = fminf(fminf(smn[o][0], smn[o][1]), fminf(smn[o][2], smn[o][3]));
        float b = fmaxf(fmaxf(smx[o][0], smx[o][1]), fmaxf(smx[o][2], smx[o][3]));
        atomicMin(&mm[o], f2key(a));
        atomicMax(&mm[o + NOCT], f2key(b));
    }
}

// K3: streaming apply. grid (1024 rows, 4 channel-groups), 256 threads.
// Each thread: 4 pixels' noise (computed once), then 12 channels of float4 R/W.
__global__ __launch_bounds__(256) void k_apply(const float4* __restrict__ img,
                                               const float* __restrict__ mixp,
                                               const float2* __restrict__ gtab,
                                               const unsigned* __restrict__ mm,
                                               float4* __restrict__ out) {
    const int i = blockIdx.x;
    const int j = threadIdx.x << 2;
    const int cbase = blockIdx.y * (NCH / 4);

    float sy = (float)i / 1023.0f;
    float sx[4];
#pragma unroll
    for (int k = 0; k < 4; ++k) sx[k] = (float)(j + k) / 1023.0f;

    const float AMPS[NOCT] = {0.1f, 0.05f, 0.025f, 0.0125f, 0.00625f};
    float ax = 0.f, ay = 0.f, az = 0.f, aw = 0.f;
#pragma unroll
    for (int o = 0; o < NOCT; ++o) {
        float n[4];
        perlin4(gtab, o, i, j, sy, sx, n);
        float mnv = key2f(mm[o]);
        float mxv = key2f(mm[o + NOCT]);
        float inv = 1.0f / (mxv - mnv);
        float sA = 2.0f * AMPS[o] * inv;
        float sB = AMPS[o] * (-2.0f * mnv * inv - 1.0f);
        ax += sA * n[0] + sB;
        ay += sA * n[1] + sB;
        az += sA * n[2] + sB;
        aw += sA * n[3] + sB;
    }
    float mix = *mixp;
    ax *= mix; ay *= mix; az *= mix; aw *= mix;

    const int plane = HH * WW / 4;  // float4 units
    int p = (i << 8) + threadIdx.x;
#pragma unroll
    for (int c = 0; c < NCH / 4; ++c) {
        int idx = (cbase + c) * plane + p;
        float4 v = img[idx];
        v.x = fminf(fmaxf(v.x + ax, 0.0f), 1.0f);
        v.y = fminf(fmaxf(v.y + ay, 0.0f), 1.0f);
        v.z = fminf(fmaxf(v.z + az, 0.0f), 1.0f);
        v.w = fminf(fmaxf(v.w + aw, 0.0f), 1.0f);
        out[idx] = v;
    }
}

extern "C" void kernel_launch(void* const* d_in, const int* in_sizes, int n_in,
                              void* d_out, int out_size, void* d_ws, size_t ws_size,
                              hipStream_t stream) {
    const float* img = (const float*)d_in[0];
    const float* mixp;
    const float* ang[NOCT];
    if (in_sizes[1] == 1) {           // dict order: image, mix, angles_0..4
        mixp = (const float*)d_in[1];
        for (int o = 0; o < NOCT; ++o) ang[o] = (const float*)d_in[2 + o];
    } else {                          // defensive: image, angles_0..4, mix
        for (int o = 0; o < NOCT; ++o) ang[o] = (const float*)d_in[1 + o];
        mixp = (const float*)d_in[6];
    }

    float2* gtab = (float2*)d_ws;                                // 5709 * 8 B
    unsigned* mm = (unsigned*)((char*)d_ws + 46080);             // 10 uints

    k_tables<<<dim3((GTAB_TOTAL + 255) / 256), dim3(256), 0, stream>>>(
        ang[0], ang[1], ang[2], ang[3], ang[4], gtab, mm);
    k_minmax<<<dim3(256), dim3(256), 0, stream>>>(gtab, mm);
    k_apply<<<dim3(HH, 4), dim3(256), 0, stream>>>(
        (const float4*)img, mixp, gtab, mm, (float4*)d_out);
}